// Round 2
// baseline (1423.931 us; speedup 1.0000x reference)
//
#include <hip/hip_runtime.h>
#include <math.h>

// ---------------------------------------------------------------------------
// VQ-VAE 3D forward. Round 2: conv/convT rewritten as "SGPR weights + direct
// global x + register blocking" — weight addresses are wave-uniform so the
// compiler emits s_load (scalar cache) and FMAs take the weight as the SGPR
// operand; x comes from global through L1/L2 (no LDS, no barriers).
// ---------------------------------------------------------------------------

// ---------------- forward conv (k=4,s=2,p=1) --------------------------------
// x: [B,CIN,DIN^3], wg: [COUT,CIN,64] (OIDHW), out: [B,COUT,DOUT^3]
// block = 256 thr = 8(w) x 8(h) x 4(d); thread owns TZ d-positions (stride 4)
// x OCG output channels. Weight reads wave-uniform -> s_load.
template<int CIN, int COUT, int DIN, int DOUT, int OCG, int TZ, bool RELU>
__global__ __launch_bounds__(256) void k_convf(const float* __restrict__ x,
                                               const float* __restrict__ wg,
                                               const float* __restrict__ bias,
                                               float* __restrict__ out) {
  constexpr int NBX = DOUT / 8, NBY = DOUT / 8, NBZ = DOUT / (4 * TZ);
  const int tid = threadIdx.x;
  const int tx = tid & 7, ty = (tid >> 3) & 7, tz = tid >> 6;
  int bb = blockIdx.x;
  const int gx = bb % NBX; bb /= NBX;
  const int gy = bb % NBY; bb /= NBY;
  const int gz = bb % NBZ; bb /= NBZ;
  const int b = bb;
  const int oc0 = blockIdx.y * OCG;
  const int ow = gx * 8 + tx, oh = gy * 8 + ty;

  int odz[TZ];
#pragma unroll
  for (int j = 0; j < TZ; ++j) odz[j] = gz * (4 * TZ) + tz + j * 4;

  float acc[TZ][OCG];
#pragma unroll
  for (int j = 0; j < TZ; ++j)
#pragma unroll
    for (int c = 0; c < OCG; ++c) acc[j][c] = 0.0f;

  const int iw0 = ow * 2 - 1, ih0 = oh * 2 - 1;

#pragma unroll 1
  for (int ci = 0; ci < CIN; ++ci) {
    const float* xb = x + (size_t)(b * CIN + ci) * (DIN * DIN * DIN);
    const float* wb = wg + ((size_t)oc0 * CIN + ci) * 64;
#pragma unroll 1
    for (int kd = 0; kd < 4; ++kd) {
#pragma unroll 1
      for (int kh = 0; kh < 4; ++kh) {
        const int ih = ih0 + kh;
        const bool vh = (unsigned)ih < (unsigned)DIN;
        float xv[TZ][4];
#pragma unroll
        for (int j = 0; j < TZ; ++j) {
          const int id = odz[j] * 2 - 1 + kd;
          const bool vd = vh && ((unsigned)id < (unsigned)DIN);
          const float* xr = xb + ((size_t)id * DIN + ih) * DIN + iw0;
#pragma unroll
          for (int kw = 0; kw < 4; ++kw) {
            const bool v = vd && ((unsigned)(iw0 + kw) < (unsigned)DIN);
            xv[j][kw] = v ? xr[kw] : 0.0f;
          }
        }
        const int tb = (kd * 4 + kh) * 4;
#pragma unroll
        for (int c = 0; c < OCG; ++c) {
          const float* wr = wb + (size_t)c * (CIN * 64) + tb;  // uniform -> s_load
          const float w0 = wr[0], w1 = wr[1], w2 = wr[2], w3 = wr[3];
#pragma unroll
          for (int j = 0; j < TZ; ++j) {
            acc[j][c] = fmaf(xv[j][0], w0, acc[j][c]);
            acc[j][c] = fmaf(xv[j][1], w1, acc[j][c]);
            acc[j][c] = fmaf(xv[j][2], w2, acc[j][c]);
            acc[j][c] = fmaf(xv[j][3], w3, acc[j][c]);
          }
        }
      }
    }
  }

  const size_t ps = (size_t)DOUT * DOUT * DOUT;
#pragma unroll
  for (int c = 0; c < OCG; ++c) {
    const float bv = bias[oc0 + c];
#pragma unroll
    for (int j = 0; j < TZ; ++j) {
      float v = acc[j][c] + bv;
      if (RELU) v = fmaxf(v, 0.0f);
      out[(size_t)(b * COUT + oc0 + c) * ps
          + ((size_t)odz[j] * DOUT + oh) * DOUT + ow] = v;
    }
  }
}

// ---------------- transposed conv (k=4,s=2,p=1), octet-per-thread -----------
// x: [B,CIN,DIN^3], wg: [CIN,COUT,64] (PyTorch layout), out: [B,COUT,(2DIN)^3]
// Thread owns the 2x2x2 output octet at (2mx+px, 2my+py, 2mz+pz) so the tap
// index k = 3 - 2*d + p is uniform -> weights via s_load. 27-point x
// neighborhood register-cached, reused across 8 outputs x OCG channels.
template<int CIN, int COUT, int DIN, int OCG, bool RELU>
__global__ __launch_bounds__(256) void k_convtf(const float* __restrict__ x,
                                                const float* __restrict__ wg,
                                                const float* __restrict__ bias,
                                                float* __restrict__ out) {
  constexpr int DOUT = 2 * DIN;
  constexpr int NBX = DIN / 8, NBY = DIN / 8, NBZ = DIN / 4;
  const int tid = threadIdx.x;
  const int tx = tid & 7, ty = (tid >> 3) & 7, tz = tid >> 6;
  int bb = blockIdx.x;
  const int gx = bb % NBX; bb /= NBX;
  const int gy = bb % NBY; bb /= NBY;
  const int gz = bb % NBZ; bb /= NBZ;
  const int b = bb;
  const int oc0 = blockIdx.y * OCG;
  const int mx = gx * 8 + tx, my = gy * 8 + ty, mz = gz * 4 + tz;

  bool v3x[3], v3y[3], v3z[3];
#pragma unroll
  for (int d = 0; d < 3; ++d) {
    v3x[d] = (unsigned)(mx - 1 + d) < (unsigned)DIN;
    v3y[d] = (unsigned)(my - 1 + d) < (unsigned)DIN;
    v3z[d] = (unsigned)(mz - 1 + d) < (unsigned)DIN;
  }

  float acc[8][OCG];
#pragma unroll
  for (int p = 0; p < 8; ++p)
#pragma unroll
    for (int c = 0; c < OCG; ++c) acc[p][c] = 0.0f;

#pragma unroll 1
  for (int ci = 0; ci < CIN; ++ci) {
    const float* xb = x + (size_t)(b * CIN + ci) * (DIN * DIN * DIN);
    float xn[3][3][3];
#pragma unroll
    for (int dz = 0; dz < 3; ++dz)
#pragma unroll
      for (int dy = 0; dy < 3; ++dy) {
        const float* xr = xb + ((size_t)(mz - 1 + dz) * DIN + (my - 1 + dy)) * DIN + (mx - 1);
        const bool vzy = v3z[dz] && v3y[dy];
#pragma unroll
        for (int dx = 0; dx < 3; ++dx)
          xn[dz][dy][dx] = (vzy && v3x[dx]) ? xr[dx] : 0.0f;
      }

    const float* wb = wg + ((size_t)ci * COUT + oc0) * 64;
#pragma unroll
    for (int p = 0; p < 8; ++p) {
      const int pz = p >> 2, py = (p >> 1) & 1, px = p & 1;
#pragma unroll
      for (int az = 0; az < 2; ++az) {
        const int dz = pz + az, kz = 3 - 2 * dz + pz;
#pragma unroll
        for (int ay = 0; ay < 2; ++ay) {
          const int dy = py + ay, ky = 3 - 2 * dy + py;
#pragma unroll
          for (int ax = 0; ax < 2; ++ax) {
            const int dx = px + ax, kx = 3 - 2 * dx + px;
            const float xv = xn[dz][dy][dx];
            const int t = (kz * 4 + ky) * 4 + kx;   // uniform
#pragma unroll
            for (int c = 0; c < OCG; ++c)
              acc[p][c] = fmaf(xv, wb[(size_t)c * 64 + t], acc[p][c]);
          }
        }
      }
    }
  }

  const size_t ps = (size_t)DOUT * DOUT * DOUT;
#pragma unroll
  for (int c = 0; c < OCG; ++c) {
    const float bv = bias[oc0 + c];
#pragma unroll
    for (int pz = 0; pz < 2; ++pz)
#pragma unroll
      for (int py = 0; py < 2; ++py) {
        const int p0 = (pz * 2 + py) * 2;
        float a0 = acc[p0][c] + bv, a1 = acc[p0 + 1][c] + bv;
        if (RELU) { a0 = fmaxf(a0, 0.0f); a1 = fmaxf(a1, 0.0f); }
        float2 v2 = make_float2(a0, a1);
        *(float2*)&out[(size_t)(b * COUT + oc0 + c) * ps
                       + ((size_t)(2 * mz + pz) * DOUT + (2 * my + py)) * DOUT
                       + 2 * mx] = v2;
      }
  }
}

// ---------------- VQ: argmin over 512 codes, gather codebook ----------------
__global__ __launch_bounds__(256) void k_vq(const float* __restrict__ ze,
                                            const float* __restrict__ cb,
                                            float* __restrict__ quant) {
  __shared__ float ct[64 * 65];
  __shared__ float zs[4][64];
  __shared__ int   bis[4];
  const int tid  = threadIdx.x;
  const int lane = tid & 63;
  const int wv   = tid >> 6;
  const int p0 = blockIdx.x * 4;
  const int b  = p0 >> 12;
  const int n0 = p0 & 4095;

  {
    const int c = tid >> 2, j = tid & 3;
    zs[j][c] = ze[((size_t)(b * 64 + c) << 12) + n0 + j];
  }

  float best = 3.4e38f;
  int bi = 0;
#pragma unroll 1
  for (int ch = 0; ch < 8; ++ch) {
    __syncthreads();
    for (int i = tid; i < 4096; i += 256) {
      const int r = i >> 6, c = i & 63;
      ct[r * 65 + c] = cb[((ch * 64 + r) << 6) + c];
    }
    __syncthreads();
    float d = 0.0f;
#pragma unroll 8
    for (int c = 0; c < 64; ++c) {
      const float t = zs[wv][c] - ct[lane * 65 + c];
      d = fmaf(t, t, d);
    }
    const int k = ch * 64 + lane;
    if (d < best) { best = d; bi = k; }
  }
#pragma unroll
  for (int off = 32; off > 0; off >>= 1) {
    const float ob = __shfl_down(best, off);
    const int   oi = __shfl_down(bi, off);
    if (ob < best || (ob == best && oi < bi)) { best = ob; bi = oi; }
  }
  if (lane == 0) bis[wv] = bi;
  __syncthreads();
  {
    const int c = tid >> 2, j = tid & 3;
    quant[((size_t)(b * 64 + c) << 12) + n0 + j] = cb[(bis[j] << 6) + c];
  }
}

// ---------------- convT3 (16->1) with LDS input tile + sigmoid --------------
__global__ __launch_bounds__(256) void k_convt3(const float* __restrict__ x,
                                                const float* __restrict__ wg,
                                                const float* __restrict__ bias,
                                                float* __restrict__ out) {
  __shared__ float xt[16 * 216];
  __shared__ float wl[16 * 64];
  const int tid = threadIdx.x;
  const int bid = blockIdx.x;
  const int bx = bid & 15, by = (bid >> 4) & 15, bz = (bid >> 8) & 15, b = bid >> 12;
  const int ix0 = bx * 4 - 1, iy0 = by * 4 - 1, iz0 = bz * 4 - 1;

  for (int i = tid; i < 1024; i += 256) wl[i] = wg[i];
  for (int i = tid; i < 16 * 216; i += 256) {
    const int ci = i / 216;
    const int r  = i % 216;
    const int lz = r / 36, ry = r % 36, ly = ry / 6, lx = ry % 6;
    const int iz = iz0 + lz, iy = iy0 + ly, ix = ix0 + lx;
    float v = 0.0f;
    if ((unsigned)iz < 64u && (unsigned)iy < 64u && (unsigned)ix < 64u)
      v = x[(size_t)(b * 16 + ci) * 262144 + ((iz * 64 + iy) * 64 + ix)];
    xt[i] = v;
  }
  __syncthreads();

  const float bv = bias[0];
  const int ox = tid & 7, oy = (tid >> 3) & 7, ozA = tid >> 6;
  const int px = ox & 1, py = oy & 1, pz = ozA & 1;
  const int lx0 = (ox >> 1) + px, ly0 = (oy >> 1) + py, lzA = (ozA >> 1) + pz;
  const int kx0 = 3 - px, kx1 = 1 - px;
  const int ky0 = 3 - py, ky1 = 1 - py;
  const int kz0 = 3 - pz, kz1 = 1 - pz;

  float accA = bv, accB = bv;
#pragma unroll 1
  for (int ci = 0; ci < 16; ++ci) {
    const float* xc = xt + ci * 216;
    const float* wc = wl + (ci << 6);
#pragma unroll
    for (int az = 0; az < 2; ++az) {
      const int kz = az ? kz1 : kz0;
      const int lza = lzA + az, lzb = lza + 2;
#pragma unroll
      for (int ay = 0; ay < 2; ++ay) {
        const int ky = ay ? ky1 : ky0;
        const int ly = ly0 + ay;
        const float* wr = wc + ((kz * 4 + ky) << 2);
        const float w0 = wr[kx0], w1 = wr[kx1];
        const float* xa  = xc + (lza * 6 + ly) * 6 + lx0;
        const float* xb2 = xc + (lzb * 6 + ly) * 6 + lx0;
        accA = fmaf(xa[0],  w0, accA);
        accA = fmaf(xa[1],  w1, accA);
        accB = fmaf(xb2[0], w0, accB);
        accB = fmaf(xb2[1], w1, accB);
      }
    }
  }
  const int gx = bx * 8 + ox, gy = by * 8 + oy;
  const size_t base = (size_t)b * 2097152;
  const float sA = 1.0f / (1.0f + expf(-accA));
  const float sB = 1.0f / (1.0f + expf(-accB));
  out[base + ((size_t)((bz * 8 + ozA)     * 128 + gy) * 128) + gx] = sA;
  out[base + ((size_t)((bz * 8 + ozA + 4) * 128 + gy) * 128) + gx] = sB;
}

// ---------------------------------------------------------------------------
extern "C" void kernel_launch(void* const* d_in, const int* in_sizes, int n_in,
                              void* d_out, int out_size, void* d_ws, size_t ws_size,
                              hipStream_t stream) {
  const float* x   = (const float*)d_in[0];
  const float* w1  = (const float*)d_in[1];
  const float* b1  = (const float*)d_in[2];
  const float* w2  = (const float*)d_in[3];
  const float* b2  = (const float*)d_in[4];
  const float* w3  = (const float*)d_in[5];
  const float* b3  = (const float*)d_in[6];
  const float* cb  = (const float*)d_in[7];
  const float* dw1 = (const float*)d_in[8];
  const float* db1 = (const float*)d_in[9];
  const float* dw2 = (const float*)d_in[10];
  const float* db2 = (const float*)d_in[11];
  const float* dw3 = (const float*)d_in[12];
  const float* db3 = (const float*)d_in[13];

  float* outf  = (float*)d_out;
  float* xhat  = outf;               // [4,1,128^3]
  float* quant = outf + 8388608;     // [4,64,16^3]
  float* ze    = outf + 9437184;     // [4,64,16^3]

  float* bufA = (float*)d_ws;        // 16,777,216 floats: y1 then d2
  float* bufB = bufA + 16777216;     //  4,194,304 floats: y2 then d1

  // encoder
  k_convf<1, 16, 128, 64, 16, 2, true><<<dim3(2048, 1), 256, 0, stream>>>(x, w1, b1, bufA);
  k_convf<16, 32, 64, 32, 16, 2, true><<<dim3(256, 2), 256, 0, stream>>>(bufA, w2, b2, bufB);
  k_convf<32, 64, 32, 16, 8, 1, false><<<dim3(64, 8), 256, 0, stream>>>(bufB, w3, b3, ze);
  // vector quantization
  k_vq<<<4096, 256, 0, stream>>>(ze, cb, quant);
  // decoder
  k_convtf<64, 32, 16, 4, true><<<dim3(64, 8), 256, 0, stream>>>(quant, dw1, db1, bufB);
  k_convtf<32, 16, 32, 4, true><<<dim3(512, 4), 256, 0, stream>>>(bufB, dw2, db2, bufA);
  k_convt3<<<16384, 256, 0, stream>>>(bufA, dw3, db3, xhat);
}

// Round 3
// 1326.798 us; speedup vs baseline: 1.0732x; 1.0732x over previous
//
#include <hip/hip_runtime.h>
#include <math.h>

// ---------------------------------------------------------------------------
// VQ-VAE 3D forward, round 3.
// Fixes vs round 2 (which was grid-occupancy-capped at 2 blocks/CU on the hot
// layers and used per-element predicated loads):
//  * every conv >= 1024 blocks (4-8 blocks/CU)
//  * padded intermediate volumes in d_ws (halo zeroed each launch) ->
//    unconditional vectorized loads, zero boundary logic in hot loops
//  * weights fetched as contiguous 16-float rows via wave-uniform addresses
//    (s_load -> SGPR operand of v_fmac)
// ---------------------------------------------------------------------------

__device__ __forceinline__ float4 ld4(const float* p) {
  float4 q; __builtin_memcpy(&q, p, 16); return q;
}
struct F3 { float x, y, z; };
__device__ __forceinline__ F3 ld3(const float* p) {
  F3 q; __builtin_memcpy(&q, p, 12); return q;
}

// ---------------- halo zeroing for padded buffers ---------------------------
// buf is NCH channel-volumes of S^3; interior is [1, D] in each dim.
template<int S, int D, int NCH>
__global__ __launch_bounds__(256) void k_zhalo(float* __restrict__ buf) {
  const int vol = S * S * S;
  const long long idx = (long long)blockIdx.x * 256 + threadIdx.x;
  if (idx >= (long long)NCH * vol) return;
  const int r = (int)(idx % vol);
  const int z = r / (S * S), y = (r / S) % S, x = r % S;
  if (z < 1 || z > D || y < 1 || y > D || x < 1 || x > D) buf[idx] = 0.0f;
}

// ---------------- forward conv (k=4,s=2,p=1) --------------------------------
// xin: [B,CIN,*] (padded stride SIN if INP else dense DIN), wg: OIDHW,
// out: [B,COUT,*] (padded SOUT if OUTP else dense DOUT).
// block 256 = 8x8x4 outputs, OCG channels per block (grid.y).
template<int CIN, int COUT, int DIN, int DOUT, int OCG, bool RELU,
         bool INP, int SIN, bool OUTP, int SOUT>
__global__ __launch_bounds__(256) void k_conv(const float* __restrict__ xin,
                                              const float* __restrict__ wg,
                                              const float* __restrict__ bias,
                                              float* __restrict__ out) {
  constexpr int NBX = DOUT / 8, NBY = DOUT / 8, NBZ = DOUT / 4;
  constexpr size_t VIN  = INP  ? (size_t)SIN * SIN * SIN : (size_t)DIN * DIN * DIN;
  constexpr size_t VOUT = OUTP ? (size_t)SOUT * SOUT * SOUT : (size_t)DOUT * DOUT * DOUT;
  const int tid = threadIdx.x;
  const int tx = tid & 7, ty = (tid >> 3) & 7, tz = tid >> 6;
  int bb = blockIdx.x;
  const int gx = bb % NBX; bb /= NBX;
  const int gy = bb % NBY; bb /= NBY;
  const int gz = bb % NBZ; bb /= NBZ;
  const int b = bb;
  const int oc0 = blockIdx.y * OCG;
  const int ow = gx * 8 + tx, oh = gy * 8 + ty, od = gz * 4 + tz;
  const int iw0 = ow * 2 - 1, ih0 = oh * 2 - 1, id0 = od * 2 - 1;

  float acc[OCG];
#pragma unroll
  for (int c = 0; c < OCG; ++c) acc[c] = 0.0f;

#pragma unroll 1
  for (int ci = 0; ci < CIN; ++ci) {
    const float* xb = xin + (size_t)(b * CIN + ci) * VIN;
    const float* wb = wg + ((size_t)oc0 * CIN + ci) * 64;
#pragma unroll 1
    for (int kd = 0; kd < 4; ++kd) {
      float4 q[4];
      if (INP) {
        // padded: indices shifted by +1, always in-bounds
        const float* rowb = xb + ((size_t)(id0 + kd + 1) * SIN + (ih0 + 1)) * SIN
                               + (iw0 + 1);
#pragma unroll
        for (int kh = 0; kh < 4; ++kh) q[kh] = ld4(rowb + (size_t)kh * SIN);
      } else {
        const int id = id0 + kd;
        const bool vd = (unsigned)id < (unsigned)DIN;
#pragma unroll
        for (int kh = 0; kh < 4; ++kh) {
          const int ih = ih0 + kh;
          const bool vh = vd && ((unsigned)ih < (unsigned)DIN);
          const float* xr = xb + ((size_t)id * DIN + ih) * DIN + iw0;
          float t0 = (vh && ((unsigned)(iw0 + 0) < (unsigned)DIN)) ? xr[0] : 0.0f;
          float t1 = (vh && ((unsigned)(iw0 + 1) < (unsigned)DIN)) ? xr[1] : 0.0f;
          float t2 = (vh && ((unsigned)(iw0 + 2) < (unsigned)DIN)) ? xr[2] : 0.0f;
          float t3 = (vh && ((unsigned)(iw0 + 3) < (unsigned)DIN)) ? xr[3] : 0.0f;
          q[kh] = make_float4(t0, t1, t2, t3);
        }
      }
#pragma unroll
      for (int c = 0; c < OCG; ++c) {
        const float* wr = wb + (size_t)c * (CIN * 64) + kd * 16;  // uniform -> s_load
        acc[c] = fmaf(q[0].x, wr[0],  acc[c]);
        acc[c] = fmaf(q[0].y, wr[1],  acc[c]);
        acc[c] = fmaf(q[0].z, wr[2],  acc[c]);
        acc[c] = fmaf(q[0].w, wr[3],  acc[c]);
        acc[c] = fmaf(q[1].x, wr[4],  acc[c]);
        acc[c] = fmaf(q[1].y, wr[5],  acc[c]);
        acc[c] = fmaf(q[1].z, wr[6],  acc[c]);
        acc[c] = fmaf(q[1].w, wr[7],  acc[c]);
        acc[c] = fmaf(q[2].x, wr[8],  acc[c]);
        acc[c] = fmaf(q[2].y, wr[9],  acc[c]);
        acc[c] = fmaf(q[2].z, wr[10], acc[c]);
        acc[c] = fmaf(q[2].w, wr[11], acc[c]);
        acc[c] = fmaf(q[3].x, wr[12], acc[c]);
        acc[c] = fmaf(q[3].y, wr[13], acc[c]);
        acc[c] = fmaf(q[3].z, wr[14], acc[c]);
        acc[c] = fmaf(q[3].w, wr[15], acc[c]);
      }
    }
  }

#pragma unroll
  for (int c = 0; c < OCG; ++c) {
    float v = acc[c] + bias[oc0 + c];
    if (RELU) v = fmaxf(v, 0.0f);
    if (OUTP)
      out[(size_t)(b * COUT + oc0 + c) * VOUT
          + ((size_t)(od + 1) * SOUT + (oh + 1)) * SOUT + (ow + 1)] = v;
    else
      out[(size_t)(b * COUT + oc0 + c) * VOUT
          + ((size_t)od * DOUT + oh) * DOUT + ow] = v;
  }
}

// ---------------- transposed conv (k=4,s=2,p=1), octet-per-thread -----------
// Both input and output padded (+1 offset). Thread owns the 2x2x2 output
// octet of m-cube (mx,my,mz); 27-point neighborhood register-cached.
template<int CIN, int COUT, int DIN, int OCG, bool RELU, int SIN, int SOUT>
__global__ __launch_bounds__(256) void k_convt(const float* __restrict__ xin,
                                               const float* __restrict__ wg,
                                               const float* __restrict__ bias,
                                               float* __restrict__ out) {
  constexpr int NBX = DIN / 8, NBY = DIN / 8, NBZ = DIN / 4;
  constexpr size_t VIN  = (size_t)SIN * SIN * SIN;
  constexpr size_t VOUT = (size_t)SOUT * SOUT * SOUT;
  const int tid = threadIdx.x;
  const int tx = tid & 7, ty = (tid >> 3) & 7, tz = tid >> 6;
  int bb = blockIdx.x;
  const int gx = bb % NBX; bb /= NBX;
  const int gy = bb % NBY; bb /= NBY;
  const int gz = bb % NBZ; bb /= NBZ;
  const int b = bb;
  const int oc0 = blockIdx.y * OCG;
  const int mx = gx * 8 + tx, my = gy * 8 + ty, mz = gz * 4 + tz;

  float acc[8][OCG];
#pragma unroll
  for (int p = 0; p < 8; ++p)
#pragma unroll
    for (int c = 0; c < OCG; ++c) acc[p][c] = 0.0f;

#pragma unroll 1
  for (int ci = 0; ci < CIN; ++ci) {
    // padded base: input index (m-1+d)+1 = m+d
    const float* xb = xin + (size_t)(b * CIN + ci) * VIN
                          + ((size_t)mz * SIN + my) * SIN + mx;
    float xn[27];
#pragma unroll
    for (int dz = 0; dz < 3; ++dz)
#pragma unroll
      for (int dy = 0; dy < 3; ++dy) {
        F3 t = ld3(xb + ((size_t)dz * SIN + dy) * SIN);
        xn[(dz * 3 + dy) * 3 + 0] = t.x;
        xn[(dz * 3 + dy) * 3 + 1] = t.y;
        xn[(dz * 3 + dy) * 3 + 2] = t.z;
      }
#pragma unroll
    for (int c = 0; c < OCG; ++c) {
      const float* wc = wg + ((size_t)ci * COUT + oc0 + c) * 64;  // uniform
#pragma unroll
      for (int p = 0; p < 8; ++p) {
        const int pz = p >> 2, py = (p >> 1) & 1, px = p & 1;
#pragma unroll
        for (int az = 0; az < 2; ++az) {
          const int dz = pz + az, kz = 3 - 2 * dz + pz;
#pragma unroll
          for (int ay = 0; ay < 2; ++ay) {
            const int dy = py + ay, ky = 3 - 2 * dy + py;
#pragma unroll
            for (int ax = 0; ax < 2; ++ax) {
              const int dx = px + ax, kx = 3 - 2 * dx + px;
              acc[p][c] = fmaf(xn[(dz * 3 + dy) * 3 + dx],
                               wc[(kz * 4 + ky) * 4 + kx], acc[p][c]);
            }
          }
        }
      }
    }
  }

#pragma unroll
  for (int c = 0; c < OCG; ++c) {
    const float bv = bias[oc0 + c];
#pragma unroll
    for (int p = 0; p < 8; ++p) {
      const int pz = p >> 2, py = (p >> 1) & 1, px = p & 1;
      float v = acc[p][c] + bv;
      if (RELU) v = fmaxf(v, 0.0f);
      out[(size_t)(b * COUT + oc0 + c) * VOUT
          + ((size_t)(2 * mz + pz + 1) * SOUT + (2 * my + py + 1)) * SOUT
          + (2 * mx + px + 1)] = v;
    }
  }
}

// ---------------- VQ: argmin over 512 codes, gather codebook ----------------
// ze: [4,64,4096] dense; writes quant (dense, d_out) and quantp (padded 20^3).
__global__ __launch_bounds__(256) void k_vq(const float* __restrict__ ze,
                                            const float* __restrict__ cb,
                                            float* __restrict__ quant,
                                            float* __restrict__ quantp) {
  __shared__ float ct[64 * 65];
  __shared__ float zs[4][64];
  __shared__ int   bis[4];
  const int tid  = threadIdx.x;
  const int lane = tid & 63;
  const int wv   = tid >> 6;
  const int p0 = blockIdx.x * 4;
  const int b  = p0 >> 12;
  const int n0 = p0 & 4095;

  {
    const int c = tid >> 2, j = tid & 3;
    zs[j][c] = ze[((size_t)(b * 64 + c) << 12) + n0 + j];
  }

  float best = 3.4e38f;
  int bi = 0;
#pragma unroll 1
  for (int ch = 0; ch < 8; ++ch) {
    __syncthreads();
    for (int i = tid; i < 4096; i += 256) {
      const int r = i >> 6, c = i & 63;
      ct[r * 65 + c] = cb[((ch * 64 + r) << 6) + c];
    }
    __syncthreads();
    float d = 0.0f;
#pragma unroll 8
    for (int c = 0; c < 64; ++c) {
      const float t = zs[wv][c] - ct[lane * 65 + c];
      d = fmaf(t, t, d);
    }
    const int k = ch * 64 + lane;
    if (d < best) { best = d; bi = k; }
  }
#pragma unroll
  for (int off = 32; off > 0; off >>= 1) {
    const float ob = __shfl_down(best, off);
    const int   oi = __shfl_down(bi, off);
    if (ob < best || (ob == best && oi < bi)) { best = ob; bi = oi; }
  }
  if (lane == 0) bis[wv] = bi;
  __syncthreads();
  {
    const int c = tid >> 2, j = tid & 3;
    const float val = cb[(bis[j] << 6) + c];
    const int n = n0 + j;
    quant[((size_t)(b * 64 + c) << 12) + n] = val;
    const int zz = n >> 8, yy = (n >> 4) & 15, xx = n & 15;
    quantp[(size_t)(b * 64 + c) * 8000
           + ((size_t)(zz + 1) * 20 + (yy + 1)) * 20 + (xx + 1)] = val;
  }
}

// ---------------- convT3 (16->1) LDS input tile + sigmoid -------------------
// x: padded [4,16,68^3], out: dense [4,1,128^3].
__global__ __launch_bounds__(256) void k_convt3(const float* __restrict__ x,
                                                const float* __restrict__ wg,
                                                const float* __restrict__ bias,
                                                float* __restrict__ out) {
  constexpr size_t VIN = (size_t)68 * 68 * 68;
  __shared__ float xt[16 * 216];
  __shared__ float wl[16 * 64];
  const int tid = threadIdx.x;
  const int bid = blockIdx.x;
  const int bx = bid & 15, by = (bid >> 4) & 15, bz = (bid >> 8) & 15, b = bid >> 12;

  for (int i = tid; i < 1024; i += 256) wl[i] = wg[i];
  for (int i = tid; i < 16 * 216; i += 256) {
    const int ci = i / 216;
    const int r  = i % 216;
    const int lz = r / 36, ry = r % 36, ly = ry / 6, lx = ry % 6;
    // padded index: (bz*4-1+lz)+1 = bz*4+lz, always in [0,67]
    xt[i] = x[(size_t)(b * 16 + ci) * VIN
              + ((size_t)(bz * 4 + lz) * 68 + (by * 4 + ly)) * 68 + (bx * 4 + lx)];
  }
  __syncthreads();

  const float bv = bias[0];
  const int ox = tid & 7, oy = (tid >> 3) & 7, ozA = tid >> 6;
  const int px = ox & 1, py = oy & 1, pz = ozA & 1;
  const int lx0 = (ox >> 1) + px, ly0 = (oy >> 1) + py, lzA = (ozA >> 1) + pz;
  const int kx0 = 3 - px, kx1 = 1 - px;
  const int ky0 = 3 - py, ky1 = 1 - py;
  const int kz0 = 3 - pz, kz1 = 1 - pz;

  float accA = bv, accB = bv;
#pragma unroll 1
  for (int ci = 0; ci < 16; ++ci) {
    const float* xc = xt + ci * 216;
    const float* wc = wl + (ci << 6);
#pragma unroll
    for (int az = 0; az < 2; ++az) {
      const int kz = az ? kz1 : kz0;
      const int lza = lzA + az, lzb = lza + 2;
#pragma unroll
      for (int ay = 0; ay < 2; ++ay) {
        const int ky = ay ? ky1 : ky0;
        const int ly = ly0 + ay;
        const float* wr = wc + ((kz * 4 + ky) << 2);
        const float w0 = wr[kx0], w1 = wr[kx1];
        const float* xa  = xc + (lza * 6 + ly) * 6 + lx0;
        const float* xb2 = xc + (lzb * 6 + ly) * 6 + lx0;
        accA = fmaf(xa[0],  w0, accA);
        accA = fmaf(xa[1],  w1, accA);
        accB = fmaf(xb2[0], w0, accB);
        accB = fmaf(xb2[1], w1, accB);
      }
    }
  }
  const int gx = bx * 8 + ox, gy = by * 8 + oy;
  const size_t base = (size_t)b * 2097152;
  const float sA = 1.0f / (1.0f + expf(-accA));
  const float sB = 1.0f / (1.0f + expf(-accB));
  out[base + ((size_t)((bz * 8 + ozA)     * 128 + gy) * 128) + gx] = sA;
  out[base + ((size_t)((bz * 8 + ozA + 4) * 128 + gy) * 128) + gx] = sB;
}

// ---------------------------------------------------------------------------
extern "C" void kernel_launch(void* const* d_in, const int* in_sizes, int n_in,
                              void* d_out, int out_size, void* d_ws, size_t ws_size,
                              hipStream_t stream) {
  const float* x   = (const float*)d_in[0];
  const float* w1  = (const float*)d_in[1];
  const float* b1  = (const float*)d_in[2];
  const float* w2  = (const float*)d_in[3];
  const float* b2  = (const float*)d_in[4];
  const float* w3  = (const float*)d_in[5];
  const float* b3  = (const float*)d_in[6];
  const float* cb  = (const float*)d_in[7];
  const float* dw1 = (const float*)d_in[8];
  const float* db1 = (const float*)d_in[9];
  const float* dw2 = (const float*)d_in[10];
  const float* db2 = (const float*)d_in[11];
  const float* dw3 = (const float*)d_in[12];
  const float* db3 = (const float*)d_in[13];

  float* outf  = (float*)d_out;
  float* xhat  = outf;               // [4,1,128^3]
  float* quant = outf + 8388608;     // [4,64,16^3]
  float* ze    = outf + 9437184;     // [4,64,16^3]

  // padded workspace regions:
  //  regionA: 64 ch-vols x 68^3  (y1, then d2)     80.5 MB
  //  regionB: 128 ch-vols x 36^3 (y2, then d1)     23.9 MB
  //  regionC: 256 ch-vols x 20^3 (quantp)           8.2 MB
  float* regA = (float*)d_ws;
  float* regB = regA + (size_t)64 * 68 * 68 * 68;
  float* regC = regB + (size_t)128 * 36 * 36 * 36;

  // zero halos (ws is re-poisoned before every launch)
  k_zhalo<68, 64, 64><<<78608, 256, 0, stream>>>(regA);
  k_zhalo<36, 32, 128><<<23328, 256, 0, stream>>>(regB);
  k_zhalo<20, 16, 256><<<8000, 256, 0, stream>>>(regC);

  // encoder
  k_conv<1, 16, 128, 64, 16, true, false, 0, true, 68>
      <<<dim3(4096, 1), 256, 0, stream>>>(x, w1, b1, regA);
  k_conv<16, 32, 64, 32, 8, true, true, 68, true, 36>
      <<<dim3(512, 4), 256, 0, stream>>>(regA, w2, b2, regB);
  k_conv<32, 64, 32, 16, 4, false, true, 36, false, 16>
      <<<dim3(64, 16), 256, 0, stream>>>(regB, w3, b3, ze);
  // vector quantization
  k_vq<<<4096, 256, 0, stream>>>(ze, cb, quant, regC);
  // decoder
  k_convt<64, 32, 16, 2, true, 20, 36>
      <<<dim3(64, 16), 256, 0, stream>>>(regC, dw1, db1, regB);
  k_convt<32, 16, 32, 4, true, 36, 68>
      <<<dim3(512, 4), 256, 0, stream>>>(regB, dw2, db2, regA);
  k_convt3<<<16384, 256, 0, stream>>>(regA, dw3, db3, xhat);
}